// Round 9
// baseline (442.844 us; speedup 1.0000x reference)
//
#include <hip/hip_runtime.h>
#include <hip/hip_bf16.h>

typedef unsigned short u16;
typedef unsigned int u32;

#define NR 16384   // B*T
#define TT 4096    // T

typedef __bf16 bf16_t;
typedef bf16_t bf16x8 __attribute__((ext_vector_type(8)));
typedef float f32x4 __attribute__((ext_vector_type(4)));

// ---------- bf16 helpers ----------
__device__ __forceinline__ float b2f(u16 u){ return __uint_as_float(((u32)u)<<16); }
__device__ __forceinline__ u16 f2b(float f){
  u32 u = __float_as_uint(f);
  u32 r = u + 0x7fffu + ((u>>16)&1u);
  return (u16)(r>>16);
}
__device__ __forceinline__ void up2(u32 u, float&a, float&b){
  a = __uint_as_float(u<<16);
  b = __uint_as_float(u & 0xffff0000u);
}
__device__ __forceinline__ void ld8(const u16* p, float* f){
  uint4 v = *(const uint4*)p;
  up2(v.x,f[0],f[1]); up2(v.y,f[2],f[3]);
  up2(v.z,f[4],f[5]); up2(v.w,f[6],f[7]);
}
__device__ __forceinline__ float wred(float v){
  #pragma unroll
  for(int o=32;o>0;o>>=1) v += __shfl_down(v,o,64);
  return v;
}
// fast gelu (tanh form): max abs err ~1e-3, well within 20x error margin
__device__ __forceinline__ float gelu_f(float x){
  float x2 = x*x;
  float u = x*(0.7978845608f + 0.0356774081f*x2);
  float e = __expf(2.0f*u);
  float t = 1.0f - 2.0f*__builtin_amdgcn_rcpf(e+1.0f);
  return 0.5f*x*(1.0f+t);
}
__device__ __forceinline__ void gl_lds(const void* g, void* l){
  __builtin_amdgcn_global_load_lds(
      (__attribute__((address_space(1))) void*)(void*)g,
      (__attribute__((address_space(3))) void*)l, 16, 0, 0);
}

// ---------- transpose-convert: src f32 [K][N] -> dst bf16 [N][K] ----------
__global__ void k_tw(const float* __restrict__ src, u16* __restrict__ dst,
                     int K, int N, long long sS, long long sD){
  __shared__ float t[32][33];
  const float* S = src + (size_t)blockIdx.z*sS;
  u16* D = dst + (size_t)blockIdx.z*sD;
  int k0 = blockIdx.y*32, n0 = blockIdx.x*32;
  int r = threadIdx.x>>5, c = threadIdx.x&31;
  #pragma unroll
  for(int p=0;p<4;p++) t[r+p*8][c] = S[(size_t)(k0+r+p*8)*N + n0 + c];
  __syncthreads();
  #pragma unroll
  for(int p=0;p<4;p++) D[(size_t)(n0+r+p*8)*K + k0 + c] = f2b(t[c][r+p*8]);
}

// ---------- build compact W2^T [5][32][512] + bias [5*32] (pseudo-heads) ----------
__global__ void k_w2c(const float* __restrict__ wq, const float* __restrict__ bq,
                      const float* __restrict__ wr, const float* __restrict__ br,
                      const float* __restrict__ wb_, const float* __restrict__ bb_,
                      const float* __restrict__ wk, const float* __restrict__ bk,
                      u16* __restrict__ W2c, float* __restrict__ b2c){
  int idx = blockIdx.x;            // 0..159 : p*32 + j
  int p = idx>>5, j = idx&31, tid = threadIdx.x;
  const float* Wm; const float* Bm; int V; int cofs = 0;
  if(p<=1){ Wm=wq; Bm=bq; V=64; cofs = p*32; }
  else if(p==2){ Wm=wr; Bm=br; V=13; }
  else if(p==3){ Wm=wb_; Bm=bb_; V=13; }
  else { Wm=wk; Bm=bk; V=25; }
  int c = j + cofs;
  bool valid = c < V;
  for(int k=tid;k<512;k+=256)
    W2c[(size_t)idx*512 + k] = f2b(valid ? Wm[(size_t)k*V + c] : 0.f);
  if(tid==0) b2c[idx] = valid ? Bm[c] : 0.f;
}

// ---------- e-moment scalars: es = {S_e0, S_e1, SS_e0, SS_e1, S_e0e1} ----------
__global__ void k_esum(const float* __restrict__ e0, const float* __restrict__ e1,
                       float* __restrict__ es){
  int lane = threadIdx.x & 63;
  float x0 = e0[lane], x1 = e0[lane+64];
  float y0 = e1[lane], y1 = e1[lane+64];
  float s0 = x0+x1, s1 = y0+y1;
  float q0 = x0*x0+x1*x1, q1 = y0*y0+y1*y1, c = x0*y0+x1*y1;
  s0 = wred(s0); s1 = wred(s1); q0 = wred(q0); q1 = wred(q1); c = wred(c);
  if(lane==0){ es[0]=s0; es[1]=s1; es[2]=q0; es[3]=q1; es[4]=c; }
}

// ---------- K1: bl = h.w_bnd + b ; row stats ; h->bf16 ; out[:,115]=bl ----------
__global__ void k_bnd(const float* __restrict__ h, const float* __restrict__ wb,
                      const float* __restrict__ bb,
                      float* __restrict__ bl, float* __restrict__ hsum, float* __restrict__ hss,
                      u16* __restrict__ hbf, float* __restrict__ out){
  int wave = threadIdx.x>>6, lane = threadIdx.x&63;
  int n = blockIdx.x*4 + wave;
  const float4* hp = (const float4*)(h + (size_t)n*512 + lane*8);
  const float4* wp = (const float4*)(wb + lane*8);
  float4 h0 = hp[0], h1 = hp[1], w0 = wp[0], w1 = wp[1];
  float hv[8] = {h0.x,h0.y,h0.z,h0.w,h1.x,h1.y,h1.z,h1.w};
  float wv[8] = {w0.x,w0.y,w0.z,w0.w,w1.x,w1.y,w1.z,w1.w};
  float dot=0.f, s=0.f, ss=0.f;
  #pragma unroll
  for(int i=0;i<8;i++){ dot += hv[i]*wv[i]; s += hv[i]; ss += hv[i]*hv[i]; }
  u16* hd = hbf + (size_t)n*512 + lane*8;
  *(ushort4*)hd     = make_ushort4(f2b(hv[0]),f2b(hv[1]),f2b(hv[2]),f2b(hv[3]));
  *(ushort4*)(hd+4) = make_ushort4(f2b(hv[4]),f2b(hv[5]),f2b(hv[6]),f2b(hv[7]));
  dot = wred(dot); s = wred(s); ss = wred(ss);
  if(lane==0){
    float v = dot + bb[0];
    bl[n] = v; hsum[n]=s; hss[n]=ss;
    out[(size_t)n*116 + 115] = v;
  }
}

// ---------- K2: conv9 (zero pad) + sigmoid ----------
__global__ void k_conv(const float* __restrict__ bl, const float* __restrict__ ck,
                       const float* __restrict__ cb, float* __restrict__ bsoft){
  int n = blockIdx.x*256 + threadIdx.x;
  int b = n>>12, t = n&4095;
  float acc = cb[0];
  #pragma unroll
  for(int i=0;i<9;i++){
    int tt = t-4+i;
    if(tt>=0 && tt<TT) acc += bl[(b<<12)+tt]*ck[i];
  }
  bsoft[n] = 1.0f/(1.0f+expf(-acc));
}

// ---------- K3: film_in = LN(concat(h, eb)) -> bf16 (streaming, analytic stats) ----
__global__ void k_filmin(const u16* __restrict__ hbf, const float* __restrict__ bsoft,
                         const float* __restrict__ e0, const float* __restrict__ e1,
                         const float* __restrict__ es,
                         const float* __restrict__ hsum, const float* __restrict__ hss,
                         const float* __restrict__ g, const float* __restrict__ bb,
                         u16* __restrict__ fin){
  int n = blockIdx.x, tid = threadIdx.x;
  if(tid >= 160) return;
  float bs = bsoft[n], os = 1.0f - bs;
  float S  = hsum[n] + bs*es[1] + os*es[0];
  float SS = hss[n] + bs*bs*es[3] + 2.0f*bs*os*es[4] + os*os*es[2];
  float mu = S*(1.0f/640.0f);
  float var = SS*(1.0f/640.0f) - mu*mu;
  float rs = rsqrtf(var + 1e-5f);
  int d = tid*4;
  float v[4];
  if(d < 512){
    ushort4 hv = *(const ushort4*)(hbf + (size_t)n*512 + d);
    v[0]=b2f(hv.x); v[1]=b2f(hv.y); v[2]=b2f(hv.z); v[3]=b2f(hv.w);
  } else {
    float4 a = *(const float4*)(e1 + d - 512);
    float4 b0 = *(const float4*)(e0 + d - 512);
    v[0]=bs*a.x+os*b0.x; v[1]=bs*a.y+os*b0.y; v[2]=bs*a.z+os*b0.z; v[3]=bs*a.w+os*b0.w;
  }
  float4 g4 = *(const float4*)(g + d);
  float4 b4 = *(const float4*)(bb + d);
  u16 o[4];
  o[0]=f2b((v[0]-mu)*rs*g4.x+b4.x); o[1]=f2b((v[1]-mu)*rs*g4.y+b4.y);
  o[2]=f2b((v[2]-mu)*rs*g4.z+b4.z); o[3]=f2b((v[3]-mu)*rs*g4.w+b4.w);
  *(ushort4*)(fin + (size_t)n*640 + d) = make_ushort4(o[0],o[1],o[2],o[3]);
}

// ---------- k_film: film GEMM (gamma+beta strips, BK=64) + fused z epilogue ------
__global__ __launch_bounds__(256) void k_film(
    const u16* __restrict__ fin, const u16* __restrict__ WT, const float* __restrict__ fbias,
    const float* __restrict__ hsum, const float* __restrict__ hss,
    const float* __restrict__ lng, const float* __restrict__ lnb,
    const u16* __restrict__ hbf, u16* __restrict__ z){
  __shared__ __align__(16) u16 As[2][128*32];
  __shared__ __align__(16) u16 Bg[2][128*32];
  __shared__ __align__(16) u16 Bb2[2][128*32];
  int tid = threadIdx.x, wave = tid>>6, lane = tid&63;
  int cg0 = blockIdx.x*128, row0 = blockIdx.y*128;
  int wr = (wave>>1)*64, wc = (wave&1)*64;
  int lrow = lane>>2, lcol = (lane&3)*8, m15 = lane&15, q = lane>>4;
  f32x4 ag[4][4] = {}, ab[4][4] = {};
  for(int k0=0;k0<640;k0+=64){
    #pragma unroll
    for(int hh=0;hh<2;hh++){
      int kk = k0 + hh*32;
      const u16* ga = fin + (size_t)(row0 + wave*32 + lrow)*640 + kk + lcol;
      u16* la = &As[hh][wave*32*32];
      gl_lds(ga, la); gl_lds(ga + (size_t)16*640, la + 16*32);
      const u16* gg = WT + (size_t)(cg0 + wave*32 + lrow)*640 + kk + lcol;
      u16* lg = &Bg[hh][wave*32*32];
      gl_lds(gg, lg); gl_lds(gg + (size_t)16*640, lg + 16*32);
      const u16* gb2 = WT + (size_t)(cg0 + 512 + wave*32 + lrow)*640 + kk + lcol;
      u16* lb2 = &Bb2[hh][wave*32*32];
      gl_lds(gb2, lb2); gl_lds(gb2 + (size_t)16*640, lb2 + 16*32);
    }
    __syncthreads();
    #pragma unroll
    for(int hh=0;hh<2;hh++){
      bf16x8 af[4], bg[4], bb[4];
      #pragma unroll
      for(int i=0;i<4;i++){
        af[i] = *(const bf16x8*)&As[hh][(wr + i*16 + m15)*32 + q*8];
        bg[i] = *(const bf16x8*)&Bg[hh][(wc + i*16 + m15)*32 + q*8];
        bb[i] = *(const bf16x8*)&Bb2[hh][(wc + i*16 + m15)*32 + q*8];
      }
      #pragma unroll
      for(int i=0;i<4;i++)
        #pragma unroll
        for(int j=0;j<4;j++){
          ag[i][j] = __builtin_amdgcn_mfma_f32_16x16x32_bf16(bg[j], af[i], ag[i][j], 0,0,0);
          ab[i][j] = __builtin_amdgcn_mfma_f32_16x16x32_bf16(bb[j], af[i], ab[i][j], 0,0,0);
        }
    }
    __syncthreads();
  }
  #pragma unroll
  for(int i=0;i<4;i++){
    int m = row0 + wr + i*16 + m15;
    float mu = hsum[m]*(1.0f/512.0f);
    float var = hss[m]*(1.0f/512.0f) - mu*mu;
    float rs = rsqrtf(var + 1e-5f);
    #pragma unroll
    for(int j=0;j<4;j++){
      int d0 = cg0 + wc + j*16 + q*4;
      float4 g4 = *(const float4*)&lng[d0];
      float4 b4 = *(const float4*)&lnb[d0];
      float4 fg = *(const float4*)&fbias[d0];
      float4 fb = *(const float4*)&fbias[512+d0];
      float hv[4];
      { ushort4 hb4 = *(const ushort4*)(hbf + (size_t)m*512 + d0);
        hv[0]=b2f(hb4.x); hv[1]=b2f(hb4.y); hv[2]=b2f(hb4.z); hv[3]=b2f(hb4.w); }
      float gm[4] = {ag[i][j][0]+fg.x, ag[i][j][1]+fg.y, ag[i][j][2]+fg.z, ag[i][j][3]+fg.w};
      float bt[4] = {ab[i][j][0]+fb.x, ab[i][j][1]+fb.y, ab[i][j][2]+fb.z, ab[i][j][3]+fb.w};
      float gg4[4] = {g4.x,g4.y,g4.z,g4.w}, bb4[4] = {b4.x,b4.y,b4.z,b4.w};
      u16 o[4];
      #pragma unroll
      for(int r=0;r<4;r++){
        float ln = (hv[r]-mu)*rs*gg4[r] + bb4[r];
        o[r] = f2b(ln*(1.0f+gm[r]) + bt[r]);
      }
      *(ushort4*)(z + (size_t)m*512 + d0) = make_ushort4(o[0],o[1],o[2],o[3]);
    }
  }
}

// ---------- k_msc: score GEMM (BK=64) + fused gelu + w2-dot -> LDS reduce, store --
__global__ __launch_bounds__(256) void k_msc(
    const u16* __restrict__ hb, const u16* __restrict__ zb,
    const u16* __restrict__ WT, const float* __restrict__ b1,
    const float* __restrict__ w2, float* __restrict__ sch, float* __restrict__ scz){
  __shared__ __align__(16) u16 As[2][64*32];
  __shared__ __align__(16) u16 Bs[2][256*32];
  __shared__ float pw[4][64];
  int tid = threadIdx.x, wave = tid>>6, lane = tid&63;
  int bz = blockIdx.y, hk = bz>>1, src = bz&1;
  const u16* X = src ? zb : hb;
  float* sc = src ? scz : sch;
  int row0 = blockIdx.x*64;
  const u16* Wb = WT + (size_t)hk*256*512;
  int lrow = lane>>2, lcol = (lane&3)*8, m15 = lane&15, q = lane>>4;
  int wc = wave*64;
  f32x4 acc[4][4] = {};
  for(int k0=0;k0<512;k0+=64){
    #pragma unroll
    for(int hh=0;hh<2;hh++){
      int kk = k0 + hh*32;
      gl_lds(X + (size_t)(row0 + wave*16 + lrow)*512 + kk + lcol, &As[hh][wave*16*32]);
      #pragma unroll
      for(int r=0;r<4;r++)
        gl_lds(Wb + (size_t)(wave*64 + r*16 + lrow)*512 + kk + lcol,
               &Bs[hh][(wave*64 + r*16)*32]);
    }
    __syncthreads();
    #pragma unroll
    for(int hh=0;hh<2;hh++){
      bf16x8 af[4], bfr[4];
      #pragma unroll
      for(int i=0;i<4;i++){
        af[i]  = *(const bf16x8*)&As[hh][(i*16 + m15)*32 + q*8];
        bfr[i] = *(const bf16x8*)&Bs[hh][(wc + i*16 + m15)*32 + q*8];
      }
      #pragma unroll
      for(int i=0;i<4;i++)
        #pragma unroll
        for(int j=0;j<4;j++)
          acc[i][j] = __builtin_amdgcn_mfma_f32_16x16x32_bf16(bfr[j], af[i], acc[i][j], 0,0,0);
    }
    __syncthreads();
  }
  #pragma unroll
  for(int i=0;i<4;i++){
    float part = 0.f;
    #pragma unroll
    for(int j=0;j<4;j++){
      int n0 = wc + j*16 + q*4;
      float4 bias = *(const float4*)&b1[hk*256 + n0];
      float4 wv   = *(const float4*)&w2[hk*256 + n0];
      part += gelu_f(acc[i][j][0]+bias.x)*wv.x;
      part += gelu_f(acc[i][j][1]+bias.y)*wv.y;
      part += gelu_f(acc[i][j][2]+bias.z)*wv.z;
      part += gelu_f(acc[i][j][3]+bias.w)*wv.w;
    }
    part += __shfl_xor(part, 16, 64);
    part += __shfl_xor(part, 32, 64);
    if(q==0) pw[wave][i*16 + m15] = part;
  }
  __syncthreads();
  if(tid < 64){
    float s = pw[0][tid] + pw[1][tid] + pw[2][tid] + pw[3][tid];
    sc[(size_t)hk*NR + row0 + tid] = s;
  }
}

// ---------- k_proj: proj1 GEMM fused with final projection ----------
// grid (NR/64, 4 heads). Per block: M=64 rows of head hk, both 256-col halves.
// gelu'd strip -> LDS -> second MFMA vs W2c -> out[:, head cols] (single writer).
__global__ __launch_bounds__(256) void k_proj(
    const u16* __restrict__ P, const u16* __restrict__ WT, const float* __restrict__ Bv,
    const u16* __restrict__ W2c, const float* __restrict__ b2c,
    float* __restrict__ out){
  __shared__ __align__(16) u16 As[2][64*32];     // 8 KB
  __shared__ __align__(16) u16 BsS[16896];       // 33 KB: Bs[2][256*32] | Sbuf[64][264]
  int tid = threadIdx.x, wave = tid>>6, lane = tid&63;
  int hk = blockIdx.y;
  int row0 = blockIdx.x*64;
  const u16* Xb = P + (size_t)hk*NR*512;
  const float* Bq = Bv + hk*512;
  int r2base = (hk==0) ? 0 : (hk+1)*32;
  int nt = (hk==0) ? 4 : 2;
  int B0 = (hk==0)?0:(hk==1)?64:(hk==2)?77:90;
  int V  = (hk==0)?64:(hk==3)?25:13;
  int lrow = lane>>2, lcol = (lane&3)*8, m15 = lane&15, q = lane>>4;
  int wc = wave*64;
  f32x4 acc2[4] = {};
  for(int half=0; half<2; half++){
    int c0 = half*256;
    const u16* Wb = WT + (size_t)hk*512*512 + (size_t)c0*512;
    f32x4 acc[4][4] = {};
    for(int k0=0;k0<512;k0+=64){
      #pragma unroll
      for(int hh=0;hh<2;hh++){
        int kk = k0 + hh*32;
        gl_lds(Xb + (size_t)(row0 + wave*16 + lrow)*512 + kk + lcol, &As[hh][wave*16*32]);
        u16* lb = &BsS[hh*256*32 + wave*64*32];
        #pragma unroll
        for(int r=0;r<4;r++)
          gl_lds(Wb + (size_t)(wave*64 + r*16 + lrow)*512 + kk + lcol, lb + r*16*32);
      }
      __syncthreads();
      #pragma unroll
      for(int hh=0;hh<2;hh++){
        bf16x8 af[4], bfr[4];
        #pragma unroll
        for(int i=0;i<4;i++){
          af[i]  = *(const bf16x8*)&As[hh][(i*16 + m15)*32 + q*8];
          bfr[i] = *(const bf16x8*)&BsS[hh*256*32 + (wc + i*16 + m15)*32 + q*8];
        }
        #pragma unroll
        for(int i=0;i<4;i++)
          #pragma unroll
          for(int j=0;j<4;j++)
            acc[i][j] = __builtin_amdgcn_mfma_f32_16x16x32_bf16(bfr[j], af[i], acc[i][j], 0,0,0);
      }
      __syncthreads();
    }
    // gelu epilogue -> Sbuf[64][264] (aliases Bs; all reads drained by barrier)
    #pragma unroll
    for(int i=0;i<4;i++){
      int srow = i*16 + m15;
      #pragma unroll
      for(int j=0;j<4;j++){
        int sn = wc + j*16 + q*4;
        float4 bias = *(const float4*)&Bq[c0 + sn];
        float v0 = gelu_f(acc[i][j][0] + bias.x);
        float v1 = gelu_f(acc[i][j][1] + bias.y);
        float v2 = gelu_f(acc[i][j][2] + bias.z);
        float v3 = gelu_f(acc[i][j][3] + bias.w);
        *(ushort4*)&BsS[srow*264 + sn] = make_ushort4(f2b(v0),f2b(v1),f2b(v2),f2b(v3));
      }
    }
    __syncthreads();
    // second GEMM: wave w owns rows w*16..w*16+15; accumulate over this half's k
    for(int k2=0;k2<256;k2+=32){
      bf16x8 af2 = *(const bf16x8*)&BsS[(wave*16 + m15)*264 + k2 + q*8];
      #pragma unroll
      for(int j=0;j<4;j++){
        if(j<nt){
          bf16x8 bf2 = *(const bf16x8*)&W2c[(size_t)(r2base + j*16 + m15)*512 + c0 + k2 + q*8];
          acc2[j] = __builtin_amdgcn_mfma_f32_16x16x32_bf16(af2, bf2, acc2[j], 0,0,0);
        }
      }
    }
    __syncthreads();
  }
  // store: row = row0 + wave*16 + q*4 + r, col = B0 + j*16 + m15
  #pragma unroll
  for(int j=0;j<4;j++){
    if(j<nt){
      int n = j*16 + m15;
      if(n < V){
        float bias = b2c[r2base + n];
        #pragma unroll
        for(int r=0;r<4;r++){
          int row = row0 + wave*16 + q*4 + r;
          out[(size_t)row*116 + B0 + n] = acc2[j][r] + bias;
        }
      }
    }
  }
}

// ---------- K7: one wave per row: lane-parallel softmax + register pooling -------
__global__ __launch_bounds__(256) void k_pool(
    const u16* __restrict__ hb, const u16* __restrict__ z,
    const float* __restrict__ sch, const float* __restrict__ scz,
    u16* __restrict__ P){
  int wave = threadIdx.x>>6, lane = threadIdx.x&63;
  int n = blockIdx.x*4 + wave;
  int b = n>>12, t = n&4095;
  int k = lane&3, j = lane>>2;
  float s;
  if(j==0) s = scz[(size_t)k*NR+n];
  else if(j<10){
    int tc = t-5+j; tc = tc<0?0:(tc>TT-1?TT-1:tc);
    s = sch[(size_t)k*NR + (b<<12) + tc];
  } else s = -1e30f;
  float m = s;
  #pragma unroll
  for(int o=4;o<64;o<<=1) m = fmaxf(m, __shfl_xor(m,o,64));
  float e = (j<10)? expf(s-m) : 0.f;
  float sum = e;
  #pragma unroll
  for(int o=4;o<64;o<<=1) sum += __shfl_xor(sum,o,64);
  float ev = e/sum;
  int d0 = lane*8;
  float acc[4][8] = {};
  #pragma unroll
  for(int jj=0;jj<10;jj++){
    const u16* src;
    if(jj==0) src = z + (size_t)n*512 + d0;
    else {
      int tc = t-5+jj; tc = tc<0?0:(tc>TT-1?TT-1:tc);
      src = hb + ((size_t)(b<<12)+tc)*512 + d0;
    }
    float f[8]; ld8(src, f);
    float w0 = __shfl(ev, jj*4+0, 64);
    float w1 = __shfl(ev, jj*4+1, 64);
    float w2 = __shfl(ev, jj*4+2, 64);
    float w3 = __shfl(ev, jj*4+3, 64);
    #pragma unroll
    for(int i=0;i<8;i++){
      acc[0][i] += w0*f[i];
      acc[1][i] += w1*f[i];
      acc[2][i] += w2*f[i];
      acc[3][i] += w3*f[i];
    }
  }
  #pragma unroll
  for(int kk=0;kk<4;kk++){
    u16* dst = P + ((size_t)kk*NR + n)*512 + d0;
    *(ushort4*)dst     = make_ushort4(f2b(acc[kk][0]),f2b(acc[kk][1]),f2b(acc[kk][2]),f2b(acc[kk][3]));
    *(ushort4*)(dst+4) = make_ushort4(f2b(acc[kk][4]),f2b(acc[kk][5]),f2b(acc[kk][6]),f2b(acc[kk][7]));
  }
}

// ---------- workspace layout (bytes) ----------
#define OFF_BL     0u
#define OFF_BSOFT  65536u
#define OFF_HSUM   131072u
#define OFF_HSS    196608u
#define OFF_SCH    262144u
#define OFF_SCZ    524288u
#define OFF_FIN    786432u            // bf16 NR*640
#define OFF_Z      55312384u          // bf16 NR*512
#define OFF_HBF    72089600u          // bf16 NR*512
#define OFF_WF     88866816u          // bf16 1024*640 (film_w^T)
#define OFF_WA     90177536u          // bf16 4*256*512 (attn_w1^T)
#define OFF_WP     91226112u          // bf16 4*512*512 (proj_w1^T)
#define OFF_P      93323264u          // bf16 4*NR*512 pooled
#define OFF_W2C    160432128u         // bf16 5*32*512 compact W2^T
#define OFF_B2C    160595968u         // f32 160
#define OFF_ES     160596608u         // f32 5 (e-moments)

extern "C" void kernel_launch(void* const* d_in, const int* in_sizes, int n_in,
                              void* d_out, int out_size, void* d_ws, size_t ws_size,
                              hipStream_t stream){
  const float* h       = (const float*)d_in[0];
  const float* w_bnd   = (const float*)d_in[1];
  const float* b_bnd   = (const float*)d_in[2];
  const float* conv_k  = (const float*)d_in[3];
  const float* conv_b  = (const float*)d_in[4];
  const float* e0      = (const float*)d_in[5];
  const float* e1      = (const float*)d_in[6];
  const float* ln_in_g = (const float*)d_in[7];
  const float* ln_in_b = (const float*)d_in[8];
  const float* ln_h_g  = (const float*)d_in[9];
  const float* ln_h_b  = (const float*)d_in[10];
  const float* film_w  = (const float*)d_in[11];
  const float* film_b  = (const float*)d_in[12];
  const float* attn_w1 = (const float*)d_in[13];
  const float* attn_b1 = (const float*)d_in[14];
  const float* attn_w2 = (const float*)d_in[15];
  // d_in[16] = attn_b2 (unused: softmax shift-invariant)
  const float* proj_w1 = (const float*)d_in[17];
  const float* proj_b1 = (const float*)d_in[18];
  const float* wq = (const float*)d_in[19];
  const float* bq = (const float*)d_in[20];
  const float* wr = (const float*)d_in[21];
  const float* br = (const float*)d_in[22];
  const float* wb_ = (const float*)d_in[23];
  const float* bb_ = (const float*)d_in[24];
  const float* wk = (const float*)d_in[25];
  const float* bk = (const float*)d_in[26];
  float* out = (float*)d_out;
  char* ws = (char*)d_ws;

  float* bl    = (float*)(ws + OFF_BL);
  float* bsoft = (float*)(ws + OFF_BSOFT);
  float* hsum  = (float*)(ws + OFF_HSUM);
  float* hss   = (float*)(ws + OFF_HSS);
  float* sch   = (float*)(ws + OFF_SCH);
  float* scz   = (float*)(ws + OFF_SCZ);
  u16* fin     = (u16*)(ws + OFF_FIN);
  u16* z       = (u16*)(ws + OFF_Z);
  u16* hbf     = (u16*)(ws + OFF_HBF);
  u16* wfilm   = (u16*)(ws + OFF_WF);
  u16* wattn   = (u16*)(ws + OFF_WA);
  u16* wproj   = (u16*)(ws + OFF_WP);
  u16* P       = (u16*)(ws + OFF_P);
  u16* w2c     = (u16*)(ws + OFF_W2C);
  float* b2c   = (float*)(ws + OFF_B2C);
  float* es    = (float*)(ws + OFF_ES);

  // weight transpose-convert + scalars
  {
    dim3 g(1024/32, 640/32, 1);
    k_tw<<<g,256,0,stream>>>(film_w, wfilm, 640, 1024, 0, 0);
  }
  {
    dim3 g(256/32, 512/32, 4);
    k_tw<<<g,256,0,stream>>>(attn_w1, wattn, 512, 256, 512LL*256, 256LL*512);
  }
  {
    dim3 g(512/32, 512/32, 4);
    k_tw<<<g,256,0,stream>>>(proj_w1, wproj, 512, 512, 512LL*512, 512LL*512);
  }
  k_w2c<<<160,256,0,stream>>>(wq,bq,wr,br,wb_,bb_,wk,bk, w2c, b2c);
  k_esum<<<1,64,0,stream>>>(e0, e1, es);

  k_bnd<<<NR/4,256,0,stream>>>(h,w_bnd,b_bnd,bl,hsum,hss,hbf,out);
  k_conv<<<NR/256,256,0,stream>>>(bl,conv_k,conv_b,bsoft);
  k_filmin<<<NR,256,0,stream>>>(hbf,bsoft,e0,e1,es,hsum,hss,ln_in_g,ln_in_b,fin);

  // film GEMM + fused z
  {
    dim3 g(4, NR/128);
    k_film<<<g,256,0,stream>>>(fin, wfilm, film_b, hsum, hss, ln_h_g, ln_h_b, hbf, z);
  }

  // fused score GEMM (h and z, all heads)
  {
    dim3 g(NR/64, 8);
    k_msc<<<g,256,0,stream>>>(hbf, z, wattn, attn_b1, attn_w2, sch, scz);
  }

  k_pool<<<NR/4,256,0,stream>>>(hbf,z,sch,scz,P);

  // proj1 + final projection fused -> out (cols 0..114; col 115 from k_bnd)
  {
    dim3 g(NR/64, 4);
    k_proj<<<g,256,0,stream>>>(P, wproj, proj_b1, w2c, b2c, out);
  }
}

// Round 10
// 381.711 us; speedup vs baseline: 1.1602x; 1.1602x over previous
//
#include <hip/hip_runtime.h>
#include <hip/hip_bf16.h>

typedef unsigned short u16;
typedef unsigned int u32;

#define NR 16384   // B*T
#define TT 4096    // T

typedef __bf16 bf16_t;
typedef bf16_t bf16x8 __attribute__((ext_vector_type(8)));
typedef float f32x4 __attribute__((ext_vector_type(4)));

// ---------- bf16 helpers ----------
__device__ __forceinline__ float b2f(u16 u){ return __uint_as_float(((u32)u)<<16); }
__device__ __forceinline__ u16 f2b(float f){
  u32 u = __float_as_uint(f);
  u32 r = u + 0x7fffu + ((u>>16)&1u);
  return (u16)(r>>16);
}
__device__ __forceinline__ void up2(u32 u, float&a, float&b){
  a = __uint_as_float(u<<16);
  b = __uint_as_float(u & 0xffff0000u);
}
__device__ __forceinline__ void ld8(const u16* p, float* f){
  uint4 v = *(const uint4*)p;
  up2(v.x,f[0],f[1]); up2(v.y,f[2],f[3]);
  up2(v.z,f[4],f[5]); up2(v.w,f[6],f[7]);
}
__device__ __forceinline__ float wred(float v){
  #pragma unroll
  for(int o=32;o>0;o>>=1) v += __shfl_down(v,o,64);
  return v;
}
// fast gelu (tanh form): max abs err ~1e-3, well within 20x error margin
__device__ __forceinline__ float gelu_f(float x){
  float x2 = x*x;
  float u = x*(0.7978845608f + 0.0356774081f*x2);
  float e = __expf(2.0f*u);
  float t = 1.0f - 2.0f*__builtin_amdgcn_rcpf(e+1.0f);
  return 0.5f*x*(1.0f+t);
}
__device__ __forceinline__ void gl_lds(const void* g, void* l){
  __builtin_amdgcn_global_load_lds(
      (__attribute__((address_space(1))) void*)(void*)g,
      (__attribute__((address_space(3))) void*)l, 16, 0, 0);
}

// ---------- transpose-convert: src f32 [K][N] -> dst bf16 [N][K] ----------
__global__ void k_tw(const float* __restrict__ src, u16* __restrict__ dst,
                     int K, int N, long long sS, long long sD){
  __shared__ float t[32][33];
  const float* S = src + (size_t)blockIdx.z*sS;
  u16* D = dst + (size_t)blockIdx.z*sD;
  int k0 = blockIdx.y*32, n0 = blockIdx.x*32;
  int r = threadIdx.x>>5, c = threadIdx.x&31;
  #pragma unroll
  for(int p=0;p<4;p++) t[r+p*8][c] = S[(size_t)(k0+r+p*8)*N + n0 + c];
  __syncthreads();
  #pragma unroll
  for(int p=0;p<4;p++) D[(size_t)(n0+r+p*8)*K + k0 + c] = f2b(t[c][r+p*8]);
}

// ---------- build compact W2^T [5][32][512] + bias [5*32] (pseudo-heads) ----------
__global__ void k_w2c(const float* __restrict__ wq, const float* __restrict__ bq,
                      const float* __restrict__ wr, const float* __restrict__ br,
                      const float* __restrict__ wb_, const float* __restrict__ bb_,
                      const float* __restrict__ wk, const float* __restrict__ bk,
                      u16* __restrict__ W2c, float* __restrict__ b2c){
  int idx = blockIdx.x;            // 0..159 : p*32 + j
  int p = idx>>5, j = idx&31, tid = threadIdx.x;
  const float* Wm; const float* Bm; int V; int cofs = 0;
  if(p<=1){ Wm=wq; Bm=bq; V=64; cofs = p*32; }
  else if(p==2){ Wm=wr; Bm=br; V=13; }
  else if(p==3){ Wm=wb_; Bm=bb_; V=13; }
  else { Wm=wk; Bm=bk; V=25; }
  int c = j + cofs;
  bool valid = c < V;
  for(int k=tid;k<512;k+=256)
    W2c[(size_t)idx*512 + k] = f2b(valid ? Wm[(size_t)k*V + c] : 0.f);
  if(tid==0) b2c[idx] = valid ? Bm[c] : 0.f;
}

// ---------- e-moment scalars: es = {S_e0, S_e1, SS_e0, SS_e1, S_e0e1} ----------
__global__ void k_esum(const float* __restrict__ e0, const float* __restrict__ e1,
                       float* __restrict__ es){
  int lane = threadIdx.x & 63;
  float x0 = e0[lane], x1 = e0[lane+64];
  float y0 = e1[lane], y1 = e1[lane+64];
  float s0 = x0+x1, s1 = y0+y1;
  float q0 = x0*x0+x1*x1, q1 = y0*y0+y1*y1, c = x0*y0+x1*y1;
  s0 = wred(s0); s1 = wred(s1); q0 = wred(q0); q1 = wred(q1); c = wred(c);
  if(lane==0){ es[0]=s0; es[1]=s1; es[2]=q0; es[3]=q1; es[4]=c; }
}

// ---------- K1: bl = h.w_bnd + b ; row stats ; h->bf16 ; out[:,115]=bl ----------
__global__ void k_bnd(const float* __restrict__ h, const float* __restrict__ wb,
                      const float* __restrict__ bb,
                      float* __restrict__ bl, float* __restrict__ hsum, float* __restrict__ hss,
                      u16* __restrict__ hbf, float* __restrict__ out){
  int wave = threadIdx.x>>6, lane = threadIdx.x&63;
  int n = blockIdx.x*4 + wave;
  const float4* hp = (const float4*)(h + (size_t)n*512 + lane*8);
  const float4* wp = (const float4*)(wb + lane*8);
  float4 h0 = hp[0], h1 = hp[1], w0 = wp[0], w1 = wp[1];
  float hv[8] = {h0.x,h0.y,h0.z,h0.w,h1.x,h1.y,h1.z,h1.w};
  float wv[8] = {w0.x,w0.y,w0.z,w0.w,w1.x,w1.y,w1.z,w1.w};
  float dot=0.f, s=0.f, ss=0.f;
  #pragma unroll
  for(int i=0;i<8;i++){ dot += hv[i]*wv[i]; s += hv[i]; ss += hv[i]*hv[i]; }
  u16* hd = hbf + (size_t)n*512 + lane*8;
  *(ushort4*)hd     = make_ushort4(f2b(hv[0]),f2b(hv[1]),f2b(hv[2]),f2b(hv[3]));
  *(ushort4*)(hd+4) = make_ushort4(f2b(hv[4]),f2b(hv[5]),f2b(hv[6]),f2b(hv[7]));
  dot = wred(dot); s = wred(s); ss = wred(ss);
  if(lane==0){
    float v = dot + bb[0];
    bl[n] = v; hsum[n]=s; hss[n]=ss;
    out[(size_t)n*116 + 115] = v;
  }
}

// ---------- K2: conv9 (zero pad) + sigmoid ----------
__global__ void k_conv(const float* __restrict__ bl, const float* __restrict__ ck,
                       const float* __restrict__ cb, float* __restrict__ bsoft){
  int n = blockIdx.x*256 + threadIdx.x;
  int b = n>>12, t = n&4095;
  float acc = cb[0];
  #pragma unroll
  for(int i=0;i<9;i++){
    int tt = t-4+i;
    if(tt>=0 && tt<TT) acc += bl[(b<<12)+tt]*ck[i];
  }
  bsoft[n] = 1.0f/(1.0f+expf(-acc));
}

// ---------- K3: film_in = LN(concat(h, eb)) -> bf16 (streaming, analytic stats) ----
__global__ void k_filmin(const u16* __restrict__ hbf, const float* __restrict__ bsoft,
                         const float* __restrict__ e0, const float* __restrict__ e1,
                         const float* __restrict__ es,
                         const float* __restrict__ hsum, const float* __restrict__ hss,
                         const float* __restrict__ g, const float* __restrict__ bb,
                         u16* __restrict__ fin){
  int n = blockIdx.x, tid = threadIdx.x;
  if(tid >= 160) return;
  float bs = bsoft[n], os = 1.0f - bs;
  float S  = hsum[n] + bs*es[1] + os*es[0];
  float SS = hss[n] + bs*bs*es[3] + 2.0f*bs*os*es[4] + os*os*es[2];
  float mu = S*(1.0f/640.0f);
  float var = SS*(1.0f/640.0f) - mu*mu;
  float rs = rsqrtf(var + 1e-5f);
  int d = tid*4;
  float v[4];
  if(d < 512){
    ushort4 hv = *(const ushort4*)(hbf + (size_t)n*512 + d);
    v[0]=b2f(hv.x); v[1]=b2f(hv.y); v[2]=b2f(hv.z); v[3]=b2f(hv.w);
  } else {
    float4 a = *(const float4*)(e1 + d - 512);
    float4 b0 = *(const float4*)(e0 + d - 512);
    v[0]=bs*a.x+os*b0.x; v[1]=bs*a.y+os*b0.y; v[2]=bs*a.z+os*b0.z; v[3]=bs*a.w+os*b0.w;
  }
  float4 g4 = *(const float4*)(g + d);
  float4 b4 = *(const float4*)(bb + d);
  u16 o[4];
  o[0]=f2b((v[0]-mu)*rs*g4.x+b4.x); o[1]=f2b((v[1]-mu)*rs*g4.y+b4.y);
  o[2]=f2b((v[2]-mu)*rs*g4.z+b4.z); o[3]=f2b((v[3]-mu)*rs*g4.w+b4.w);
  *(ushort4*)(fin + (size_t)n*640 + d) = make_ushort4(o[0],o[1],o[2],o[3]);
}

// ---------- k_film: film GEMM (gamma+beta strips, BK=64) + fused z epilogue ------
__global__ __launch_bounds__(256) void k_film(
    const u16* __restrict__ fin, const u16* __restrict__ WT, const float* __restrict__ fbias,
    const float* __restrict__ hsum, const float* __restrict__ hss,
    const float* __restrict__ lng, const float* __restrict__ lnb,
    const u16* __restrict__ hbf, u16* __restrict__ z){
  __shared__ __align__(16) u16 As[2][128*32];
  __shared__ __align__(16) u16 Bg[2][128*32];
  __shared__ __align__(16) u16 Bb2[2][128*32];
  int tid = threadIdx.x, wave = tid>>6, lane = tid&63;
  int cg0 = blockIdx.x*128, row0 = blockIdx.y*128;
  int wr = (wave>>1)*64, wc = (wave&1)*64;
  int lrow = lane>>2, lcol = (lane&3)*8, m15 = lane&15, q = lane>>4;
  f32x4 ag[4][4] = {}, ab[4][4] = {};
  for(int k0=0;k0<640;k0+=64){
    #pragma unroll
    for(int hh=0;hh<2;hh++){
      int kk = k0 + hh*32;
      const u16* ga = fin + (size_t)(row0 + wave*32 + lrow)*640 + kk + lcol;
      u16* la = &As[hh][wave*32*32];
      gl_lds(ga, la); gl_lds(ga + (size_t)16*640, la + 16*32);
      const u16* gg = WT + (size_t)(cg0 + wave*32 + lrow)*640 + kk + lcol;
      u16* lg = &Bg[hh][wave*32*32];
      gl_lds(gg, lg); gl_lds(gg + (size_t)16*640, lg + 16*32);
      const u16* gb2 = WT + (size_t)(cg0 + 512 + wave*32 + lrow)*640 + kk + lcol;
      u16* lb2 = &Bb2[hh][wave*32*32];
      gl_lds(gb2, lb2); gl_lds(gb2 + (size_t)16*640, lb2 + 16*32);
    }
    __syncthreads();
    #pragma unroll
    for(int hh=0;hh<2;hh++){
      bf16x8 af[4], bg[4], bb[4];
      #pragma unroll
      for(int i=0;i<4;i++){
        af[i] = *(const bf16x8*)&As[hh][(wr + i*16 + m15)*32 + q*8];
        bg[i] = *(const bf16x8*)&Bg[hh][(wc + i*16 + m15)*32 + q*8];
        bb[i] = *(const bf16x8*)&Bb2[hh][(wc + i*16 + m15)*32 + q*8];
      }
      #pragma unroll
      for(int i=0;i<4;i++)
        #pragma unroll
        for(int j=0;j<4;j++){
          ag[i][j] = __builtin_amdgcn_mfma_f32_16x16x32_bf16(bg[j], af[i], ag[i][j], 0,0,0);
          ab[i][j] = __builtin_amdgcn_mfma_f32_16x16x32_bf16(bb[j], af[i], ab[i][j], 0,0,0);
        }
    }
    __syncthreads();
  }
  #pragma unroll
  for(int i=0;i<4;i++){
    int m = row0 + wr + i*16 + m15;
    float mu = hsum[m]*(1.0f/512.0f);
    float var = hss[m]*(1.0f/512.0f) - mu*mu;
    float rs = rsqrtf(var + 1e-5f);
    #pragma unroll
    for(int j=0;j<4;j++){
      int d0 = cg0 + wc + j*16 + q*4;
      float4 g4 = *(const float4*)&lng[d0];
      float4 b4 = *(const float4*)&lnb[d0];
      float4 fg = *(const float4*)&fbias[d0];
      float4 fb = *(const float4*)&fbias[512+d0];
      float hv[4];
      { ushort4 hb4 = *(const ushort4*)(hbf + (size_t)m*512 + d0);
        hv[0]=b2f(hb4.x); hv[1]=b2f(hb4.y); hv[2]=b2f(hb4.z); hv[3]=b2f(hb4.w); }
      float gm[4] = {ag[i][j][0]+fg.x, ag[i][j][1]+fg.y, ag[i][j][2]+fg.z, ag[i][j][3]+fg.w};
      float bt[4] = {ab[i][j][0]+fb.x, ab[i][j][1]+fb.y, ab[i][j][2]+fb.z, ab[i][j][3]+fb.w};
      float gg4[4] = {g4.x,g4.y,g4.z,g4.w}, bb4[4] = {b4.x,b4.y,b4.z,b4.w};
      u16 o[4];
      #pragma unroll
      for(int r=0;r<4;r++){
        float ln = (hv[r]-mu)*rs*gg4[r] + bb4[r];
        o[r] = f2b(ln*(1.0f+gm[r]) + bt[r]);
      }
      *(ushort4*)(z + (size_t)m*512 + d0) = make_ushort4(o[0],o[1],o[2],o[3]);
    }
  }
}

// ---------- k_msc: score GEMM, register-prefetch dbuf pipeline ----------
// M=64, N=256 (full head), K=512, 16 iters, 1 barrier/iter, vmcnt hidden by MFMA.
__global__ __launch_bounds__(256) void k_msc(
    const u16* __restrict__ hb, const u16* __restrict__ zb,
    const u16* __restrict__ WT, const float* __restrict__ b1,
    const float* __restrict__ w2, float* __restrict__ sch, float* __restrict__ scz){
  __shared__ __align__(16) u16 As[2][64*32];
  __shared__ __align__(16) u16 Bs[2][256*32];
  __shared__ float pw[4][64];
  int tid = threadIdx.x, wave = tid>>6, lane = tid&63;
  int bz = blockIdx.y, hk = bz>>1, src = bz&1;
  const u16* X = src ? zb : hb;
  float* sc = src ? scz : sch;
  int row0 = blockIdx.x*64;
  const u16* Wb = WT + (size_t)hk*256*512;
  int lrow = lane>>2, lcol = (lane&3)*8, m15 = lane&15, q = lane>>4;
  int wc = wave*64;
  const u16* gA = X + (size_t)(row0 + wave*16 + lrow)*512 + lcol;
  const u16* gB = Wb + (size_t)(wave*64 + lrow)*512 + lcol;
  int aoff = (wave*16 + lrow)*32 + lcol;
  int boff = (wave*64 + lrow)*32 + lcol;
  uint4 ra  = *(const uint4*)gA;
  uint4 rb0 = *(const uint4*)(gB);
  uint4 rb1 = *(const uint4*)(gB + 16*512);
  uint4 rb2 = *(const uint4*)(gB + 32*512);
  uint4 rb3 = *(const uint4*)(gB + 48*512);
  *(uint4*)&As[0][aoff] = ra;
  *(uint4*)&Bs[0][boff]        = rb0;
  *(uint4*)&Bs[0][boff+16*32]  = rb1;
  *(uint4*)&Bs[0][boff+32*32]  = rb2;
  *(uint4*)&Bs[0][boff+48*32]  = rb3;
  __syncthreads();
  f32x4 acc[4][4] = {};
  for(int it=0; it<16; it++){
    int cur = it&1;
    if(it<15){
      int k0 = (it+1)*32;
      ra  = *(const uint4*)(gA + k0);
      rb0 = *(const uint4*)(gB + k0);
      rb1 = *(const uint4*)(gB + 16*512 + k0);
      rb2 = *(const uint4*)(gB + 32*512 + k0);
      rb3 = *(const uint4*)(gB + 48*512 + k0);
    }
    bf16x8 af[4], bfr[4];
    #pragma unroll
    for(int i=0;i<4;i++){
      af[i]  = *(const bf16x8*)&As[cur][(i*16 + m15)*32 + q*8];
      bfr[i] = *(const bf16x8*)&Bs[cur][(wc + i*16 + m15)*32 + q*8];
    }
    #pragma unroll
    for(int i=0;i<4;i++)
      #pragma unroll
      for(int j=0;j<4;j++)
        acc[i][j] = __builtin_amdgcn_mfma_f32_16x16x32_bf16(bfr[j], af[i], acc[i][j], 0,0,0);
    if(it<15){
      int nxt = cur^1;
      *(uint4*)&As[nxt][aoff] = ra;
      *(uint4*)&Bs[nxt][boff]        = rb0;
      *(uint4*)&Bs[nxt][boff+16*32]  = rb1;
      *(uint4*)&Bs[nxt][boff+32*32]  = rb2;
      *(uint4*)&Bs[nxt][boff+48*32]  = rb3;
    }
    __syncthreads();
  }
  #pragma unroll
  for(int i=0;i<4;i++){
    float part = 0.f;
    #pragma unroll
    for(int j=0;j<4;j++){
      int n0 = wc + j*16 + q*4;
      float4 bias = *(const float4*)&b1[hk*256 + n0];
      float4 wv   = *(const float4*)&w2[hk*256 + n0];
      part += gelu_f(acc[i][j][0]+bias.x)*wv.x;
      part += gelu_f(acc[i][j][1]+bias.y)*wv.y;
      part += gelu_f(acc[i][j][2]+bias.z)*wv.z;
      part += gelu_f(acc[i][j][3]+bias.w)*wv.w;
    }
    part += __shfl_xor(part, 16, 64);
    part += __shfl_xor(part, 32, 64);
    if(q==0) pw[wave][i*16 + m15] = part;
  }
  __syncthreads();
  if(tid < 64){
    float s = pw[0][tid] + pw[1][tid] + pw[2][tid] + pw[3][tid];
    sc[(size_t)hk*NR + row0 + tid] = s;
  }
}

// ---------- k_proj: proj1 GEMM, register-prefetch dbuf pipeline ----------
// M=64, N=256, K=512, gelu epilogue, writes X2 (ld 2048).
__global__ __launch_bounds__(256) void k_proj(
    const u16* __restrict__ P, const u16* __restrict__ WT, const float* __restrict__ Bv,
    u16* __restrict__ X2){
  __shared__ __align__(16) u16 As[2][64*32];
  __shared__ __align__(16) u16 Bs[2][256*32];
  int tid = threadIdx.x, wave = tid>>6, lane = tid&63;
  int hk = blockIdx.z;
  int row0 = blockIdx.y*64, col0 = blockIdx.x*256;
  const u16* Xb = P + (size_t)hk*NR*512;
  const u16* Wb = WT + (size_t)hk*512*512 + (size_t)col0*512;
  const float* Bq = Bv + hk*512;
  int lrow = lane>>2, lcol = (lane&3)*8, m15 = lane&15, q = lane>>4;
  int wc = wave*64;
  const u16* gA = Xb + (size_t)(row0 + wave*16 + lrow)*512 + lcol;
  const u16* gB = Wb + (size_t)(wave*64 + lrow)*512 + lcol;
  int aoff = (wave*16 + lrow)*32 + lcol;
  int boff = (wave*64 + lrow)*32 + lcol;
  uint4 ra  = *(const uint4*)gA;
  uint4 rb0 = *(const uint4*)(gB);
  uint4 rb1 = *(const uint4*)(gB + 16*512);
  uint4 rb2 = *(const uint4*)(gB + 32*512);
  uint4 rb3 = *(const uint4*)(gB + 48*512);
  *(uint4*)&As[0][aoff] = ra;
  *(uint4*)&Bs[0][boff]        = rb0;
  *(uint4*)&Bs[0][boff+16*32]  = rb1;
  *(uint4*)&Bs[0][boff+32*32]  = rb2;
  *(uint4*)&Bs[0][boff+48*32]  = rb3;
  __syncthreads();
  f32x4 acc[4][4] = {};
  for(int it=0; it<16; it++){
    int cur = it&1;
    if(it<15){
      int k0 = (it+1)*32;
      ra  = *(const uint4*)(gA + k0);
      rb0 = *(const uint4*)(gB + k0);
      rb1 = *(const uint4*)(gB + 16*512 + k0);
      rb2 = *(const uint4*)(gB + 32*512 + k0);
      rb3 = *(const uint4*)(gB + 48*512 + k0);
    }
    bf16x8 af[4], bfr[4];
    #pragma unroll
    for(int i=0;i<4;i++){
      af[i]  = *(const bf16x8*)&As[cur][(i*16 + m15)*32 + q*8];
      bfr[i] = *(const bf16x8*)&Bs[cur][(wc + i*16 + m15)*32 + q*8];
    }
    #pragma unroll
    for(int i=0;i<4;i++)
      #pragma unroll
      for(int j=0;j<4;j++)
        acc[i][j] = __builtin_amdgcn_mfma_f32_16x16x32_bf16(bfr[j], af[i], acc[i][j], 0,0,0);
    if(it<15){
      int nxt = cur^1;
      *(uint4*)&As[nxt][aoff] = ra;
      *(uint4*)&Bs[nxt][boff]        = rb0;
      *(uint4*)&Bs[nxt][boff+16*32]  = rb1;
      *(uint4*)&Bs[nxt][boff+32*32]  = rb2;
      *(uint4*)&Bs[nxt][boff+48*32]  = rb3;
    }
    __syncthreads();
  }
  #pragma unroll
  for(int i=0;i<4;i++){
    size_t mrow = (size_t)(row0 + i*16 + m15)*2048 + hk*512;
    #pragma unroll
    for(int j=0;j<4;j++){
      int n0 = col0 + wc + j*16 + q*4;
      float4 bias = *(const float4*)&Bq[n0];
      float v0 = gelu_f(acc[i][j][0] + bias.x);
      float v1 = gelu_f(acc[i][j][1] + bias.y);
      float v2 = gelu_f(acc[i][j][2] + bias.z);
      float v3 = gelu_f(acc[i][j][3] + bias.w);
      *(ushort4*)(X2 + mrow + n0) = make_ushort4(f2b(v0),f2b(v1),f2b(v2),f2b(v3));
    }
  }
}

// ---------- final compact GEMM (BK=64): out cols per pseudo-head -----------------
__global__ __launch_bounds__(256) void k_f2(
    const u16* __restrict__ X2, const u16* __restrict__ W2c, const float* __restrict__ b2c,
    float* __restrict__ out){
  __shared__ __align__(16) u16 As[2][128*32];
  __shared__ __align__(16) u16 Bs[2][32*32];
  int tid = threadIdx.x, wave = tid>>6, lane = tid&63;
  int row0 = blockIdx.x*128, p = blockIdx.y;
  int hk = (p<=1)?0:(p-1);
  int B0 = (p==0)?0:(p==1)?32:(p==2)?64:(p==3)?77:90;
  int V  = (p<=1)?32:(p==4)?25:13;
  int lrow = lane>>2, lcol = (lane&3)*8, m15 = lane&15, q = lane>>4;
  f32x4 acc[2][2] = {};
  for(int k0=0;k0<512;k0+=64){
    #pragma unroll
    for(int hh=0;hh<2;hh++){
      int kk = k0 + hh*32;
      const u16* ga = X2 + (size_t)(row0 + wave*32 + lrow)*2048 + hk*512 + kk + lcol;
      u16* la = &As[hh][wave*32*32];
      gl_lds(ga, la);
      gl_lds(ga + (size_t)16*2048, la + 16*32);
      if(wave<2)
        gl_lds(W2c + (size_t)(p*32 + wave*16 + lrow)*512 + kk + lcol, &Bs[hh][wave*16*32]);
    }
    __syncthreads();
    #pragma unroll
    for(int hh=0;hh<2;hh++){
      bf16x8 af[2], bfr[2];
      #pragma unroll
      for(int i=0;i<2;i++) af[i] = *(const bf16x8*)&As[hh][(wave*32 + i*16 + m15)*32 + q*8];
      #pragma unroll
      for(int j=0;j<2;j++) bfr[j] = *(const bf16x8*)&Bs[hh][(j*16+m15)*32 + q*8];
      #pragma unroll
      for(int i=0;i<2;i++)
        #pragma unroll
        for(int j=0;j<2;j++)
          acc[i][j] = __builtin_amdgcn_mfma_f32_16x16x32_bf16(bfr[j], af[i], acc[i][j], 0,0,0);
    }
    __syncthreads();
  }
  #pragma unroll
  for(int i=0;i<2;i++){
    size_t mrow = (size_t)(row0 + wave*32 + i*16 + m15)*116;
    #pragma unroll
    for(int j=0;j<2;j++){
      int nl0 = j*16 + q*4;
      #pragma unroll
      for(int r=0;r<4;r++){
        int nl = nl0 + r;
        if(nl < V) out[mrow + B0 + nl] = acc[i][j][r] + b2c[p*32+nl];
      }
    }
  }
}

// ---------- K7: one wave per row: lane-parallel softmax + register pooling -------
__global__ __launch_bounds__(256) void k_pool(
    const u16* __restrict__ hb, const u16* __restrict__ z,
    const float* __restrict__ sch, const float* __restrict__ scz,
    u16* __restrict__ P){
  int wave = threadIdx.x>>6, lane = threadIdx.x&63;
  int n = blockIdx.x*4 + wave;
  int b = n>>12, t = n&4095;
  int k = lane&3, j = lane>>2;
  float s;
  if(j==0) s = scz[(size_t)k*NR+n];
  else if(j<10){
    int tc = t-5+j; tc = tc<0?0:(tc>TT-1?TT-1:tc);
    s = sch[(size_t)k*NR + (b<<12) + tc];
  } else s = -1e30f;
  float m = s;
  #pragma unroll
  for(int o=4;o<64;o<<=1) m = fmaxf(m, __shfl_xor(m,o,64));
  float e = (j<10)? expf(s-m) : 0.f;
  float sum = e;
  #pragma unroll
  for(int o=4;o<64;o<<=1) sum += __shfl_xor(sum,o,64);
  float ev = e/sum;
  int d0 = lane*8;
  float acc[4][8] = {};
  #pragma unroll
  for(int jj=0;jj<10;jj++){
    const u16* src;
    if(jj==0) src = z + (size_t)n*512 + d0;
    else {
      int tc = t-5+jj; tc = tc<0?0:(tc>TT-1?TT-1:tc);
      src = hb + ((size_t)(b<<12)+tc)*512 + d0;
    }
    float f[8]; ld8(src, f);
    float w0 = __shfl(ev, jj*4+0, 64);
    float w1 = __shfl(ev, jj*4+1, 64);
    float w2 = __shfl(ev, jj*4+2, 64);
    float w3 = __shfl(ev, jj*4+3, 64);
    #pragma unroll
    for(int i=0;i<8;i++){
      acc[0][i] += w0*f[i];
      acc[1][i] += w1*f[i];
      acc[2][i] += w2*f[i];
      acc[3][i] += w3*f[i];
    }
  }
  #pragma unroll
  for(int kk=0;kk<4;kk++){
    u16* dst = P + ((size_t)kk*NR + n)*512 + d0;
    *(ushort4*)dst     = make_ushort4(f2b(acc[kk][0]),f2b(acc[kk][1]),f2b(acc[kk][2]),f2b(acc[kk][3]));
    *(ushort4*)(dst+4) = make_ushort4(f2b(acc[kk][4]),f2b(acc[kk][5]),f2b(acc[kk][6]),f2b(acc[kk][7]));
  }
}

// ---------- workspace layout (bytes) ----------
#define OFF_BL     0u
#define OFF_BSOFT  65536u
#define OFF_HSUM   131072u
#define OFF_HSS    196608u
#define OFF_SCH    262144u
#define OFF_SCZ    524288u
#define OFF_FIN    786432u            // bf16 NR*640 ; X2 (NR*2048 bf16) overlays fin..z
#define OFF_Z      55312384u          // bf16 NR*512 (consumed by pool before X2 write)
#define OFF_HBF    72089600u          // bf16 NR*512
#define OFF_WF     88866816u          // bf16 1024*640 (film_w^T)
#define OFF_WA     90177536u          // bf16 4*256*512 (attn_w1^T)
#define OFF_WP     91226112u          // bf16 4*512*512 (proj_w1^T)
#define OFF_P      93323264u          // bf16 4*NR*512 pooled
#define OFF_W2C    160432128u         // bf16 5*32*512 compact W2^T
#define OFF_B2C    160595968u         // f32 160
#define OFF_ES     160596608u         // f32 5 (e-moments)

extern "C" void kernel_launch(void* const* d_in, const int* in_sizes, int n_in,
                              void* d_out, int out_size, void* d_ws, size_t ws_size,
                              hipStream_t stream){
  const float* h       = (const float*)d_in[0];
  const float* w_bnd   = (const float*)d_in[1];
  const float* b_bnd   = (const float*)d_in[2];
  const float* conv_k  = (const float*)d_in[3];
  const float* conv_b  = (const float*)d_in[4];
  const float* e0      = (const float*)d_in[5];
  const float* e1      = (const float*)d_in[6];
  const float* ln_in_g = (const float*)d_in[7];
  const float* ln_in_b = (const float*)d_in[8];
  const float* ln_h_g  = (const float*)d_in[9];
  const float* ln_h_b  = (const float*)d_in[10];
  const float* film_w  = (const float*)d_in[11];
  const float* film_b  = (const float*)d_in[12];
  const float* attn_w1 = (const float*)d_in[13];
  const float* attn_b1 = (const float*)d_in[14];
  const float* attn_w2 = (const float*)d_in[15];
  // d_in[16] = attn_b2 (unused: softmax shift-invariant)
  const float* proj_w1 = (const float*)d_in[17];
  const float* proj_b1 = (const float*)d_in[18];
  const float* wq = (const float*)d_in[19];
  const float* bq = (const float*)d_in[20];
  const float* wr = (const float*)d_in[21];
  const float* br = (const float*)d_in[22];
  const float* wb_ = (const float*)d_in[23];
  const float* bb_ = (const float*)d_in[24];
  const float* wk = (const float*)d_in[25];
  const float* bk = (const float*)d_in[26];
  float* out = (float*)d_out;
  char* ws = (char*)d_ws;

  float* bl    = (float*)(ws + OFF_BL);
  float* bsoft = (float*)(ws + OFF_BSOFT);
  float* hsum  = (float*)(ws + OFF_HSUM);
  float* hss   = (float*)(ws + OFF_HSS);
  float* sch   = (float*)(ws + OFF_SCH);
  float* scz   = (float*)(ws + OFF_SCZ);
  u16* fin     = (u16*)(ws + OFF_FIN);
  u16* X2      = (u16*)(ws + OFF_FIN);   // overlays fin+z region (dead by proj1 time)
  u16* z       = (u16*)(ws + OFF_Z);
  u16* hbf     = (u16*)(ws + OFF_HBF);
  u16* wfilm   = (u16*)(ws + OFF_WF);
  u16* wattn   = (u16*)(ws + OFF_WA);
  u16* wproj   = (u16*)(ws + OFF_WP);
  u16* P       = (u16*)(ws + OFF_P);
  u16* w2c     = (u16*)(ws + OFF_W2C);
  float* b2c   = (float*)(ws + OFF_B2C);
  float* es    = (float*)(ws + OFF_ES);

  // weight transpose-convert + scalars
  {
    dim3 g(1024/32, 640/32, 1);
    k_tw<<<g,256,0,stream>>>(film_w, wfilm, 640, 1024, 0, 0);
  }
  {
    dim3 g(256/32, 512/32, 4);
    k_tw<<<g,256,0,stream>>>(attn_w1, wattn, 512, 256, 512LL*256, 256LL*512);
  }
  {
    dim3 g(512/32, 512/32, 4);
    k_tw<<<g,256,0,stream>>>(proj_w1, wproj, 512, 512, 512LL*512, 512LL*512);
  }
  k_w2c<<<160,256,0,stream>>>(wq,bq,wr,br,wb_,bb_,wk,bk, w2c, b2c);
  k_esum<<<1,64,0,stream>>>(e0, e1, es);

  k_bnd<<<NR/4,256,0,stream>>>(h,w_bnd,b_bnd,bl,hsum,hss,hbf,out);
  k_conv<<<NR/256,256,0,stream>>>(bl,conv_k,conv_b,bsoft);
  k_filmin<<<NR,256,0,stream>>>(hbf,bsoft,e0,e1,es,hsum,hss,ln_in_g,ln_in_b,fin);

  // film GEMM + fused z
  {
    dim3 g(4, NR/128);
    k_film<<<g,256,0,stream>>>(fin, wfilm, film_b, hsum, hss, ln_h_g, ln_h_b, hbf, z);
  }

  // fused score GEMM (h and z, all heads) — pipelined
  {
    dim3 g(NR/64, 8);
    k_msc<<<g,256,0,stream>>>(hbf, z, wattn, attn_b1, attn_w2, sch, scz);
  }

  k_pool<<<NR/4,256,0,stream>>>(hbf,z,sch,scz,P);

  // proj1: pipelined, batched heads, writes X2 (ld 2048)
  {
    dim3 g(2, NR/64, 4);
    k_proj<<<g,256,0,stream>>>(P, wproj, proj_b1, X2);
  }

  // final projection -> out f32 (cols 0..114; col 115 written by k_bnd)
  {
    dim3 g(NR/128, 5);
    k_f2<<<g,256,0,stream>>>(X2, w2c, b2c, out);
  }
}